// Round 1
// baseline (568.570 us; speedup 1.0000x reference)
//
#include <hip/hip_runtime.h>

#define N_NODES 100000
#define M_EDGES 1600000
#define CH 64

// ---------------- degree ----------------
__global__ __launch_bounds__(256) void k_deg_init(float* __restrict__ deg) {
    int i = blockIdx.x * blockDim.x + threadIdx.x;
    if (i < N_NODES) deg[i] = 1.0f;  // self-loop contributes 1
}

__global__ __launch_bounds__(256) void k_deg_count(const int* __restrict__ col, float* __restrict__ deg) {
    int e = blockIdx.x * blockDim.x + threadIdx.x;
    if (e < M_EDGES) atomicAdd(&deg[col[e]], 1.0f);
}

__global__ __launch_bounds__(256) void k_dis(float* __restrict__ deg) {
    int i = blockIdx.x * blockDim.x + threadIdx.x;
    if (i < N_NODES) deg[i] = 1.0f / sqrtf(deg[i]);  // deg >= 1, no inf
}

// ---------------- h = x @ W ----------------
// block = 256 threads, 64 rows per block. W (16KB) + x-tile (16.25KB) in LDS.
__global__ __launch_bounds__(256) void k_gemm(const float* __restrict__ x, const float* __restrict__ W,
                                              float* __restrict__ h) {
    __shared__ float sW[64][64];
    __shared__ float sX[64][65];  // +1 pad
    int tid = threadIdx.x;
    int row0 = blockIdx.x * 64;

    for (int i = tid; i < 64 * 64; i += 256) sW[i >> 6][i & 63] = W[i];
    for (int i = tid; i < 64 * 64; i += 256) {
        int r = i >> 6, c = i & 63;
        int gr = row0 + r;
        sX[r][c] = (gr < N_NODES) ? x[gr * 64 + c] : 0.0f;
    }
    __syncthreads();

    int r = tid >> 2;            // 0..63 local row
    int c0 = (tid & 3) * 16;     // col group of 16
    float acc[16];
#pragma unroll
    for (int j = 0; j < 16; j++) acc[j] = 0.0f;
    for (int k = 0; k < 64; k++) {
        float xv = sX[r][k];
#pragma unroll
        for (int j = 0; j < 16; j++) acc[j] += xv * sW[k][c0 + j];
    }
    int gr = row0 + r;
    if (gr < N_NODES) {
        float4* dst = reinterpret_cast<float4*>(&h[gr * 64 + c0]);
#pragma unroll
        for (int j4 = 0; j4 < 4; j4++)
            dst[j4] = make_float4(acc[j4 * 4 + 0], acc[j4 * 4 + 1], acc[j4 * 4 + 2], acc[j4 * 4 + 3]);
    }
}

// ---------------- SpMM scatter: one wave per edge, lane = channel ----------------
__global__ __launch_bounds__(256) void k_scatter(const int* __restrict__ row, const int* __restrict__ col,
                                                 const float* __restrict__ dis, const float* __restrict__ h,
                                                 float* __restrict__ out) {
    long long gtid = (long long)blockIdx.x * blockDim.x + threadIdx.x;
    int e = (int)(gtid >> 6);
    int lane = threadIdx.x & 63;
    if (e >= M_EDGES) return;
    int r = row[e];  // wave-uniform broadcast loads
    int c = col[e];
    float norm = dis[r] * dis[c];
    float v = norm * h[(long long)r * CH + lane];
    atomicAdd(&out[(long long)c * CH + lane], v);
}

// ---------------- self-loop + bias ----------------
__global__ __launch_bounds__(256) void k_selfloop(const float* __restrict__ dis, const float* __restrict__ h,
                                                  const float* __restrict__ b, float* __restrict__ out) {
    int i = blockIdx.x * blockDim.x + threadIdx.x;
    if (i < N_NODES * CH) {
        int node = i >> 6;
        float d = dis[node];
        out[i] += d * d * h[i] + b[i & 63];
    }
}

extern "C" void kernel_launch(void* const* d_in, const int* in_sizes, int n_in,
                              void* d_out, int out_size, void* d_ws, size_t ws_size,
                              hipStream_t stream) {
    const float* x  = (const float*)d_in[0];
    const int*   ei = (const int*)d_in[1];   // [2, M] flat: row = ei[0:M], col = ei[M:2M]
    const float* W  = (const float*)d_in[2];
    const float* b  = (const float*)d_in[3];
    float* out = (float*)d_out;

    // workspace layout: dis (N floats, rounded to 512KB) | h (N*64 floats)
    float* dis = (float*)d_ws;
    float* h   = (float*)((char*)d_ws + (512 * 1024));

    const int* row = ei;
    const int* col = ei + M_EDGES;

    hipMemsetAsync(d_out, 0, (size_t)out_size * sizeof(float), stream);

    k_deg_init<<<(N_NODES + 255) / 256, 256, 0, stream>>>(dis);
    k_deg_count<<<(M_EDGES + 255) / 256, 256, 0, stream>>>(col, dis);
    k_dis<<<(N_NODES + 255) / 256, 256, 0, stream>>>(dis);

    k_gemm<<<(N_NODES + 63) / 64, 256, 0, stream>>>(x, W, h);

    long long scatter_threads = (long long)M_EDGES * 64;
    int scatter_blocks = (int)((scatter_threads + 255) / 256);
    k_scatter<<<scatter_blocks, 256, 0, stream>>>(row, col, dis, h, out);

    k_selfloop<<<(N_NODES * CH + 255) / 256, 256, 0, stream>>>(dis, h, b, out);
}

// Round 2
// 379.150 us; speedup vs baseline: 1.4996x; 1.4996x over previous
//
#include <hip/hip_runtime.h>

#define N_NODES 100000
#define M_EDGES 1600000
#define CH 64
#define SCAN_B 256
#define NBLK ((N_NODES + SCAN_B - 1) / SCAN_B)  // 391 scan blocks

// ---------- 1. histogram of target degrees (excl. self-loop) ----------
__global__ __launch_bounds__(256) void k_hist(const int* __restrict__ col, int* __restrict__ cnt) {
    int e = blockIdx.x * blockDim.x + threadIdx.x;
    if (e < M_EDGES) atomicAdd(&cnt[col[e]], 1);
}

// ---------- 2. dis = 1/sqrt(deg), deg = cnt + 1 (self-loop) ----------
__global__ __launch_bounds__(256) void k_dis(const int* __restrict__ cnt, float* __restrict__ dis) {
    int i = blockIdx.x * blockDim.x + threadIdx.x;
    if (i < N_NODES) dis[i] = 1.0f / sqrtf((float)(cnt[i] + 1));
}

// ---------- 3. exclusive scan of cnt -> base (3 kernels) ----------
__global__ __launch_bounds__(SCAN_B) void k_scan1(const int* __restrict__ cnt, int* __restrict__ base,
                                                  int* __restrict__ bsum) {
    __shared__ int s[SCAN_B];
    int gid = blockIdx.x * SCAN_B + threadIdx.x;
    int v = (gid < N_NODES) ? cnt[gid] : 0;
    s[threadIdx.x] = v;
    __syncthreads();
    for (int off = 1; off < SCAN_B; off <<= 1) {
        int t = (threadIdx.x >= off) ? s[threadIdx.x - off] : 0;
        __syncthreads();
        s[threadIdx.x] += t;
        __syncthreads();
    }
    if (gid < N_NODES) base[gid] = s[threadIdx.x] - v;  // exclusive within block
    if (threadIdx.x == SCAN_B - 1) bsum[blockIdx.x] = s[SCAN_B - 1];
}

__global__ __launch_bounds__(512) void k_scan2(int* __restrict__ bsum) {
    __shared__ int s[512];
    int v = (threadIdx.x < NBLK) ? bsum[threadIdx.x] : 0;
    s[threadIdx.x] = v;
    __syncthreads();
    for (int off = 1; off < 512; off <<= 1) {
        int t = (threadIdx.x >= off) ? s[threadIdx.x - off] : 0;
        __syncthreads();
        s[threadIdx.x] += t;
        __syncthreads();
    }
    if (threadIdx.x < NBLK) bsum[threadIdx.x] = s[threadIdx.x] - v;  // exclusive block offsets
}

__global__ __launch_bounds__(SCAN_B) void k_scan3(int* __restrict__ base, const int* __restrict__ bsum,
                                                  int* __restrict__ cursor) {
    int gid = blockIdx.x * SCAN_B + threadIdx.x;
    if (gid < N_NODES) {
        int bse = base[gid] + bsum[blockIdx.x];
        base[gid] = bse;
        cursor[gid] = bse;
    }
}

// ---------- 4. counting-sort edges by target ----------
__global__ __launch_bounds__(256) void k_edge_scatter(const int* __restrict__ row, const int* __restrict__ col,
                                                      int* __restrict__ cursor, int* __restrict__ srow) {
    int e = blockIdx.x * blockDim.x + threadIdx.x;
    if (e < M_EDGES) {
        int c = col[e];
        int pos = atomicAdd(&cursor[c], 1);
        srow[pos] = row[e];
    }
}

// ---------- 5. g = dis[r] * (x @ W)  (GEMM with scale epilogue) ----------
__global__ __launch_bounds__(256) void k_gemm_g(const float* __restrict__ x, const float* __restrict__ W,
                                                const float* __restrict__ dis, float* __restrict__ g) {
    __shared__ float sW[64][64];
    __shared__ float sX[64][65];
    int tid = threadIdx.x;
    int row0 = blockIdx.x * 64;

    for (int i = tid; i < 64 * 64; i += 256) sW[i >> 6][i & 63] = W[i];
    for (int i = tid; i < 64 * 64; i += 256) {
        int r = i >> 6, c = i & 63;
        int gr = row0 + r;
        sX[r][c] = (gr < N_NODES) ? x[gr * 64 + c] : 0.0f;
    }
    __syncthreads();

    int r = tid >> 2;
    int c0 = (tid & 3) * 16;
    float acc[16];
#pragma unroll
    for (int j = 0; j < 16; j++) acc[j] = 0.0f;
    for (int k = 0; k < 64; k++) {
        float xv = sX[r][k];
#pragma unroll
        for (int j = 0; j < 16; j++) acc[j] += xv * sW[k][c0 + j];
    }
    int gr = row0 + r;
    if (gr < N_NODES) {
        float d = dis[gr];
        float4* dst = reinterpret_cast<float4*>(&g[gr * 64 + c0]);
#pragma unroll
        for (int j4 = 0; j4 < 4; j4++)
            dst[j4] = make_float4(d * acc[j4 * 4 + 0], d * acc[j4 * 4 + 1],
                                  d * acc[j4 * 4 + 2], d * acc[j4 * 4 + 3]);
    }
}

// ---------- 6. per-node aggregation: wave per node, lane = channel ----------
// out[c] = dis[c] * (sum_e g[srow_e] + g[c]) + b
__global__ __launch_bounds__(256) void k_aggregate(const int* __restrict__ base, const int* __restrict__ cend,
                                                   const int* __restrict__ srow, const float* __restrict__ dis,
                                                   const float* __restrict__ g, const float* __restrict__ b,
                                                   float* __restrict__ out) {
    int node = blockIdx.x * 4 + (threadIdx.x >> 6);
    int lane = threadIdx.x & 63;
    if (node >= N_NODES) return;
    int s0 = base[node];
    int e0 = cend[node];  // cursor after scatter == base + cnt
    float acc = g[(size_t)node * CH + lane];  // self-loop term
    int i = s0;
    for (; i + 4 <= e0; i += 4) {
        int r0 = srow[i], r1 = srow[i + 1], r2 = srow[i + 2], r3 = srow[i + 3];
        float v0 = g[(size_t)r0 * CH + lane];
        float v1 = g[(size_t)r1 * CH + lane];
        float v2 = g[(size_t)r2 * CH + lane];
        float v3 = g[(size_t)r3 * CH + lane];
        acc += v0;
        acc += v1;
        acc += v2;
        acc += v3;
    }
    for (; i < e0; i++) acc += g[(size_t)srow[i] * CH + lane];
    out[(size_t)node * CH + lane] = dis[node] * acc + b[lane];
}

extern "C" void kernel_launch(void* const* d_in, const int* in_sizes, int n_in,
                              void* d_out, int out_size, void* d_ws, size_t ws_size,
                              hipStream_t stream) {
    const float* x  = (const float*)d_in[0];
    const int*   ei = (const int*)d_in[1];  // [2, M] flat
    const float* W  = (const float*)d_in[2];
    const float* b  = (const float*)d_in[3];
    float* out = (float*)d_out;

    const int* row = ei;
    const int* col = ei + M_EDGES;

    // workspace layout (bytes):
    char* ws = (char*)d_ws;
    int*   cnt    = (int*)(ws + 0);                    // 400,384 B
    float* dis    = (float*)(ws + (512 << 10));        // 400,000 B
    int*   base   = (int*)(ws + (1024 << 10));         // 400,000 B
    int*   cursor = (int*)(ws + (1536 << 10));         // 400,000 B
    int*   bsum   = (int*)(ws + (2048 << 10));         // 1,564 B
    float* g      = (float*)(ws + (4096 << 10));       // 25,600,000 B
    int*   srow   = (int*)(ws + (4096 << 10) + 25600000);  // 6,400,000 B  (~36.2 MB total)

    hipMemsetAsync(cnt, 0, N_NODES * sizeof(int), stream);

    k_hist<<<(M_EDGES + 255) / 256, 256, 0, stream>>>(col, cnt);
    k_dis<<<(N_NODES + 255) / 256, 256, 0, stream>>>(cnt, dis);

    k_scan1<<<NBLK, SCAN_B, 0, stream>>>(cnt, base, bsum);
    k_scan2<<<1, 512, 0, stream>>>(bsum);
    k_scan3<<<NBLK, SCAN_B, 0, stream>>>(base, bsum, cursor);

    k_gemm_g<<<(N_NODES + 63) / 64, 256, 0, stream>>>(x, W, dis, g);

    k_edge_scatter<<<(M_EDGES + 255) / 256, 256, 0, stream>>>(row, col, cursor, srow);

    // after scatter, cursor[c] == base[c] + cnt[c] == end offset
    k_aggregate<<<(N_NODES + 3) / 4, 256, 0, stream>>>(base, cursor, srow, dis, g, b, out);
}